// Round 4
// baseline (260.778 us; speedup 1.0000x reference)
//
#include <hip/hip_runtime.h>

#define N_EDGES 800000
#define N_NODES 50000
#define D 64                 // D_FEAT == EDGE_DIM == 64, K = 2*D = 128

typedef __attribute__((ext_vector_type(8))) short bf16x8;  // 8 bf16 = 16 B
typedef __attribute__((ext_vector_type(4))) float f32x4;   // MFMA accumulator

// f32 -> bf16 round-to-nearest-even (finite inputs)
__device__ __forceinline__ unsigned short f2bf(float f) {
    unsigned int u = __float_as_uint(f);
    u += 0x7fffu + ((u >> 16) & 1u);
    return (unsigned short)(u >> 16);
}
__device__ __forceinline__ unsigned int pack2(float a, float b) {
    return (unsigned int)f2bf(a) | ((unsigned int)f2bf(b) << 16);
}

// Prep (runs every call; ws re-poisoned each iter):
//  (a) node_feats (50000x64 f32) -> bf16 table (6.4 MB)
//  (b) W (128x64 f32) -> per-lane MFMA B-fragment order: 1024 x 16B entries.
//      entry idx = (ki*4+nt)*64 + l, l = q*16+m:
//      frag[j] = bf16(W[ki*32+q*8+j][nt*16+m]), j=0..7
__global__ __launch_bounds__(256) void prep(
    const float* __restrict__ nf, const float* __restrict__ W,
    unsigned short* __restrict__ nodes_bf, unsigned short* __restrict__ wfrag)
{
    if (blockIdx.x == gridDim.x - 1) {
#pragma unroll
        for (int i = 0; i < 4; ++i) {
            const int idx = i * 256 + threadIdx.x;     // 0..1023
            const int ki = idx >> 8;
            const int nt = (idx >> 6) & 3;
            const int l  = idx & 63;
            const int m  = l & 15, q = l >> 4;
            const int kbase = ki * 32 + q * 8;
            const int n = nt * 16 + m;
            unsigned short* dst = wfrag + idx * 8;
#pragma unroll
            for (int j = 0; j < 8; ++j)
                dst[j] = f2bf(W[(kbase + j) * D + n]);
        }
    } else {
        const long base = ((long)blockIdx.x * 256 + threadIdx.x) * 8;
        if (base < (long)N_NODES * D) {
            const float4 lo = *(const float4*)(nf + base);
            const float4 hi = *(const float4*)(nf + base + 4);
            uint4 p;
            p.x = pack2(lo.x, lo.y);
            p.y = pack2(lo.z, lo.w);
            p.z = pack2(hi.x, hi.y);
            p.w = pack2(hi.z, hi.w);
            *(uint4*)(nodes_bf + base) = p;
        }
    }
}

// One wave = 16 edges (single 16x16 m-tile, full n=64). Block = 4 waves.
// Small wave state (acc=16 VGPR, 4 up-front gathers) -> high occupancy,
// single gather-latency exposure per wave.
__global__ __launch_bounds__(256, 5) void edge_mlp(
    const unsigned short* __restrict__ nodes_bf,  // [N_NODES][64] bf16
    const bf16x8*        __restrict__ wfrag,      // [1024] B-fragments, 16 KB
    const int*   __restrict__ senders,
    const int*   __restrict__ receivers,
    const float* __restrict__ bias,
    float*       __restrict__ out)                // [N_EDGES][64] f32
{
    __shared__ bf16x8 lds_b[1024];                // 16 KB, fragment order

    // Stage B-fragments: 4 coalesced 16B/lane loads; lane-contiguous LDS
    // (2-way bank aliasing only -> conflict-free on gfx950).
#pragma unroll
    for (int i = 0; i < 4; ++i) {
        const int idx = i * 256 + threadIdx.x;
        lds_b[idx] = wfrag[idx];
    }
    __syncthreads();

    const int lane = threadIdx.x & 63;
    const int m    = lane & 15;   // edge-in-tile / A row / B col / C col
    const int q    = lane >> 4;   // quad: k-slice owner / C row group
    const long wid = (long)blockIdx.x * 4 + (threadIdx.x >> 6);
    const long e0  = wid * 16;    // 800000/16 = 50000 waves exact

    // Direct per-lane index loads: 16 consecutive ints, one 64B segment,
    // hardware-broadcast across the 4 quads. No shuffles needed.
    const int nr = receivers[e0 + m];
    const int ns = senders[e0 + m];

    // All 4 A-gathers issued up-front (one latency exposure per wave).
    // Each instr: 16 distinct node rows x 64 B contiguous = 16 full segments.
    const unsigned short* rrow = nodes_bf + (long)nr * D + q * 8;
    const unsigned short* srow = nodes_bf + (long)ns * D + q * 8;
    bf16x8 afrag[4];
    afrag[0] = *(const bf16x8*)(rrow);        // ki=0: recv k 0..31
    afrag[1] = *(const bf16x8*)(rrow + 32);   // ki=1: recv k 32..63
    afrag[2] = *(const bf16x8*)(srow);        // ki=2: send k 0..31
    afrag[3] = *(const bf16x8*)(srow + 32);   // ki=3: send k 32..63

    f32x4 acc[4];
#pragma unroll
    for (int nt = 0; nt < 4; ++nt) acc[nt] = (f32x4)0.0f;

#pragma unroll
    for (int ki = 0; ki < 4; ++ki) {
#pragma unroll
        for (int nt = 0; nt < 4; ++nt)
            acc[nt] = __builtin_amdgcn_mfma_f32_16x16x32_bf16(
                afrag[ki], lds_b[(ki * 4 + nt) * 64 + lane], acc[nt], 0, 0, 0);
    }

    // Epilogue: C/D layout col = m (n within tile), row = q*4 + r (edge).
    float bv[4];
#pragma unroll
    for (int nt = 0; nt < 4; ++nt) bv[nt] = bias[nt * 16 + m];

#pragma unroll
    for (int r = 0; r < 4; ++r) {
        float* op = out + (e0 + q * 4 + r) * D + m;
#pragma unroll
        for (int nt = 0; nt < 4; ++nt) {
            const float x  = acc[nt][r] + bv[nt];
            const float ax = __builtin_fabsf(x);
            const float t  = __expf(-2.0f * ax);           // (0,1]: no overflow
            float y = (1.0f - t) * __builtin_amdgcn_rcpf(1.0f + t);
            y = __builtin_copysignf(y, x);
            __builtin_nontemporal_store(y, op + nt * 16);  // out never re-read
        }
    }
}

extern "C" void kernel_launch(void* const* d_in, const int* in_sizes, int n_in,
                              void* d_out, int out_size, void* d_ws, size_t ws_size,
                              hipStream_t stream) {
    const float* node_feats = (const float*)d_in[0];
    const int*   senders    = (const int*)d_in[1];
    const int*   receivers  = (const int*)d_in[2];
    const float* W          = (const float*)d_in[3];
    const float* bias       = (const float*)d_in[4];
    float*       out        = (float*)d_out;

    // ws layout: [0, 6.4MB) bf16 node table (16B-aligned); then wfrag 16 KB
    unsigned short* nodes_bf = (unsigned short*)d_ws;
    unsigned short* wfrag    = (unsigned short*)((char*)d_ws + (size_t)N_NODES * D * 2);

    const int node_blocks = ((N_NODES * D / 8) + 255) / 256;   // 1563
    prep<<<node_blocks + 1, 256, 0, stream>>>(node_feats, W, nodes_bf, wfrag);

    // 16 edges/wave, 4 waves/block -> 64 edges/block; 800000/64 = 12500 exact
    const int n_blocks = N_EDGES / 64;
    edge_mlp<<<n_blocks, 256, 0, stream>>>(nodes_bf, (const bf16x8*)wfrag,
                                           senders, receivers, bias, out);
}